// Round 8
// baseline (287.478 us; speedup 1.0000x reference)
//
#include <hip/hip_runtime.h>
#include <stdint.h>
#include <math.h>

// Problem constants (fixed by setup_inputs: B=4, N=4096, H=2048, L=64, K=8)
constexpr int H     = 2048;
constexpr int L     = 64;
constexpr int K_SEL = 8;

// Direct-to-register MFMA geometry (r8): block = 256 thr (4 waves), 16 rows x
// 64 experts. grid 1024 = 4 blocks/CU = 4 waves/SIMD (r7 lesson: 2 waves/SIMD
// left ~500-900cy x-load latency exposed -> 60-70us vs ~15us floors).
// Wave w owns k-chunks [16w,16w+16); per-chunk: 10 loads -> cvt -> 12 MFMAs,
// with manual 1-deep register double-buffer (two named Frag sets, unroll-2).
constexpr int RPB   = 16;        // rows per block
constexpr int NCH   = 16;        // k-chunks per wave (64 total / 4 waves)

// EPS: bf16 hi/lo split noise sigma ~3e-6; 1e-4 = >30 sigma. Flagged rows
// (~200) get exact fp64 recompute.
constexpr float EPS_GAP = 1e-4f;

// ws layout (4-byte units)
constexpr int WS_COUNTS = 0;         // uint[65]: per-expert counts + [64]=active rows
constexpr int WS_NFIX   = 128;       // uint: fixup-row count
constexpr int WS_DONE   = 192;       // uint: fixup block done-counter (fused finalize)
constexpr int WS_LIST   = 256;       // uint[16384]: fixup row indices
constexpr int WS_WT     = 16640;     // float[2048*64]: W^T for coalesced fp64 fixup
constexpr int WS_WHC    = 147712;    // short[64*2048]: W hi bf16, chunked [c][e][32]
constexpr int WS_WLC    = 213248;    // short[64*2048]: W lo bf16, same layout

typedef __attribute__((ext_vector_type(8))) short bf16x8;
typedef __attribute__((ext_vector_type(4))) float f32x4;

// hi = RNE-bf16(x); lo = bf16(x - hi) (truncated; residual <= 2^-17|x|)
__device__ __forceinline__ void cvt_hi_lo(float c, short& h, short& l)
{
    unsigned u  = __float_as_uint(c);
    unsigned hb = (u + 0x7fffu + ((u >> 16) & 1u)) >> 16;
    float hf    = __uint_as_float(hb << 16);
    float lof   = c - hf;                      // exact in fp32
    h = (short)hb;
    l = (short)(__float_as_uint(lof) >> 16);
}

__device__ __forceinline__ void cvt8(const float4& u0, const float4& u1,
                                     bf16x8& h, bf16x8& l)
{
    short hh, ll;
    cvt_hi_lo(u0.x, hh, ll); h[0] = hh; l[0] = ll;
    cvt_hi_lo(u0.y, hh, ll); h[1] = hh; l[1] = ll;
    cvt_hi_lo(u0.z, hh, ll); h[2] = hh; l[2] = ll;
    cvt_hi_lo(u0.w, hh, ll); h[3] = hh; l[3] = ll;
    cvt_hi_lo(u1.x, hh, ll); h[4] = hh; l[4] = ll;
    cvt_hi_lo(u1.y, hh, ll); h[5] = hh; l[5] = ll;
    cvt_hi_lo(u1.z, hh, ll); h[6] = hh; l[6] = ll;
    cvt_hi_lo(u1.w, hh, ll); h[7] = hh; l[7] = ll;
}

// 3-product hi/lo MFMA: c += ah*bh + ah*bl + al*bh
__device__ __forceinline__ f32x4 mm3(const bf16x8& ah, const bf16x8& al,
                                     const bf16x8& bh, const bf16x8& bl, f32x4 c)
{
    c = __builtin_amdgcn_mfma_f32_16x16x32_bf16(ah, bh, c, 0, 0, 0);
    c = __builtin_amdgcn_mfma_f32_16x16x32_bf16(ah, bl, c, 0, 0, 0);
    c = __builtin_amdgcn_mfma_f32_16x16x32_bf16(al, bh, c, 0, 0, 0);
    return c;
}

// one k-chunk's register batch (all members named -> stays in VGPRs)
struct Frag {
    float4 a0, a1;
    bf16x8 bh0, bh1, bh2, bh3, bl0, bl1, bl2, bl3;
};

__device__ __forceinline__ void load_frag(Frag& f, const float* xp0,
                                          const short* whp, const short* wlp,
                                          int c)
{
    const int xo = 32 * c, wo = 2048 * c;
    f.a0  = *(const float4*)(xp0 + xo);
    f.a1  = *(const float4*)(xp0 + xo + 4);
    f.bh0 = *(const bf16x8*)(whp + wo);
    f.bh1 = *(const bf16x8*)(whp + wo + 512);
    f.bh2 = *(const bf16x8*)(whp + wo + 1024);
    f.bh3 = *(const bf16x8*)(whp + wo + 1536);
    f.bl0 = *(const bf16x8*)(wlp + wo);
    f.bl1 = *(const bf16x8*)(wlp + wo + 512);
    f.bl2 = *(const bf16x8*)(wlp + wo + 1024);
    f.bl3 = *(const bf16x8*)(wlp + wo + 1536);
}

__device__ __forceinline__ void consume(const Frag& f, f32x4& c0, f32x4& c1,
                                        f32x4& c2, f32x4& c3)
{
    bf16x8 ah, al;
    cvt8(f.a0, f.a1, ah, al);
    c0 = mm3(ah, al, f.bh0, f.bl0, c0);
    c1 = mm3(ah, al, f.bh1, f.bl1, c1);
    c2 = mm3(ah, al, f.bh2, f.bl2, c2);
    c3 = mm3(ah, al, f.bh3, f.bl3, c3);
}

// ---------------------------------------------------------------- prep ----
// blocks [0,32): transpose W -> Wt (fp64 fixup path); block 32: zero counters;
// blocks [33,65): convert W -> chunked bf16 hi/lo [kchunk][expert][32].
__global__ __launch_bounds__(256)
void prep(const float* __restrict__ Wr, float* __restrict__ Wt,
          unsigned int* __restrict__ wsu, short* __restrict__ whc,
          short* __restrict__ wlc)
{
    const int t = threadIdx.x, b = blockIdx.x;
    if (b == 32) {
        if (t < L + 1) wsu[WS_COUNTS + t] = 0u;
        if (t == 0)    wsu[WS_NFIX] = 0u;
        if (t == 1)    wsu[WS_DONE] = 0u;
        return;
    }
    if (b >= 33) {   // 32 blocks x 2 experts each; 512 float4 per expert
        const int z = b - 33;
        const int e = 2 * z + (t >> 7);
        const int idx = t & 127;
        #pragma unroll
        for (int u = 0; u < 4; ++u) {
            const int f4i = idx + 128 * u;         // 0..511
            const int k   = 4 * f4i;
            const float4 v = ((const float4*)(Wr + (size_t)e * H))[f4i];
            short4 hh, ll;
            cvt_hi_lo(v.x, hh.x, ll.x);
            cvt_hi_lo(v.y, hh.y, ll.y);
            cvt_hi_lo(v.z, hh.z, ll.z);
            cvt_hi_lo(v.w, hh.w, ll.w);
            const int c  = k >> 5, kk = k & 31;
            const int di = (c * 64 + e) * 32 + kk;
            *(short4*)(whc + di) = hh;
            *(short4*)(wlc + di) = ll;
        }
        return;
    }
    __shared__ float tile[64 * 65];
    const int k0 = b * 64;
    {
        const int l = t >> 2, kq = (t & 3) * 16;
        #pragma unroll
        for (int j = 0; j < 4; ++j) {
            float4 v = *(const float4*)(Wr + (size_t)l * H + k0 + kq + 4 * j);
            int k = kq + 4 * j;
            tile[(k + 0) * 65 + l] = v.x;
            tile[(k + 1) * 65 + l] = v.y;
            tile[(k + 2) * 65 + l] = v.z;
            tile[(k + 3) * 65 + l] = v.w;
        }
    }
    __syncthreads();
    {
        const int k = t >> 2, lq = (t & 3) * 16;
        #pragma unroll
        for (int j = 0; j < 4; ++j) {
            int l2 = lq + 4 * j;
            float4 o = make_float4(tile[k * 65 + l2], tile[k * 65 + l2 + 1],
                                   tile[k * 65 + l2 + 2], tile[k * 65 + l2 + 3]);
            *(float4*)(Wt + (size_t)(k0 + k) * L + l2) = o;
        }
    }
}

// ---------------------------------------------------------------- main ----
__global__ __launch_bounds__(256, 4)
void router_mfma(const float* __restrict__ x, const short* __restrict__ whc,
                 const short* __restrict__ wlc, const float* __restrict__ bias,
                 const unsigned char* __restrict__ am,
                 float* __restrict__ out_sel, float* __restrict__ out_probs,
                 unsigned int* __restrict__ g_counts, unsigned int* __restrict__ nfix,
                 unsigned int* __restrict__ list)
{
    __shared__ __align__(16) float lg[4 * RPB * 68];   // 17,408 B: 4 wave-partials
    __shared__ float bs[L];
    __shared__ unsigned int cnt[L + 1];

    const int t  = threadIdx.x;
    const int R0 = blockIdx.x * RPB;
    const int w  = t >> 6, l = t & 63;
    const int fr = l & 15;            // fragment row/col index (row R0+fr)
    const int kg = l >> 4;            // k-group 0..3
    const int kb = 8 * kg;            // k-base within a 32-k chunk

    if (t < L)     bs[t]  = bias[t];
    if (t < L + 1) cnt[t] = 0;

    f32x4 acc0 = {}, acc1 = {}, acc2 = {}, acc3 = {};

    const float* xp0 = x + (size_t)(R0 + fr) * H + kb;
    const short* whp = whc + fr * 32 + kb;
    const short* wlp = wlc + fr * 32 + kb;

    // wave w covers chunks [16w, 16w+16); manual 1-deep prefetch, unroll-2.
    {
        const int c0 = NCH * w;
        Frag fA, fB;
        load_frag(fA, xp0, whp, wlp, c0);
        #pragma unroll
        for (int ci = 0; ci < NCH; ci += 2) {
            load_frag(fB, xp0, whp, wlp, c0 + ci + 1);
            consume(fA, acc0, acc1, acc2, acc3);
            if (ci + 2 < NCH) load_frag(fA, xp0, whp, wlp, c0 + ci + 2);
            consume(fB, acc0, acc1, acc2, acc3);
        }
    }

    // park partials: D layout col=lane&15, row=4*(lane>>4)+reg [m89-verified]
    {
        float* lgw = lg + w * (RPB * 68);
        const int rb = 4 * kg;
        #pragma unroll
        for (int r = 0; r < 4; ++r) {
            lgw[(rb + r) * 68 + fr     ] = acc0[r];
            lgw[(rb + r) * 68 + fr + 16] = acc1[r];
            lgw[(rb + r) * 68 + fr + 32] = acc2[r];
            lgw[(rb + r) * 68 + fr + 48] = acc3[r];
        }
    }
    __syncthreads();

    // 4-way merge into lg[0] (1088 floats = 4.25 * 256)
    #pragma unroll
    for (int q = 0; q < 5; ++q) {
        const int p = t + 256 * q;
        if (p < RPB * 68)
            lg[p] = (lg[p] + lg[RPB * 68 + p]) + (lg[2 * RPB * 68 + p] + lg[3 * RPB * 68 + p]);
    }
    __syncthreads();

    // ---- top-9 epilogue: 8 lanes per row (proven r4/r6/r7 structure)
    if (t < 8 * RPB) {
        const int tj   = t & 7;
        const int lrow = t >> 3;             // 0..15
        const int grow = R0 + lrow;

        float rv[8], lv[8];
        {
            const float* lp = &lg[lrow * 68 + 8 * tj];
            const float4 v0 = *(const float4*)(lp);
            const float4 v1 = *(const float4*)(lp + 4);
            rv[0] = v0.x; rv[1] = v0.y; rv[2] = v0.z; rv[3] = v0.w;
            rv[4] = v1.x; rv[5] = v1.y; rv[6] = v1.z; rv[7] = v1.w;
            #pragma unroll
            for (int i = 0; i < 8; ++i) lv[i] = rv[i] + bs[8 * tj + i];
        }

        unsigned msk = 0;
        int   selidx[K_SEL];
        float selraw[K_SEL];
        float prev = 0.f, gmin = INFINITY;

        #pragma unroll
        for (int kk = 0; kk < K_SEL + 1; ++kk) {     // 9 rounds: gap rank8->rank9
            float best = -INFINITY; int bi = 1 << 30; float braw = 0.f;
            #pragma unroll
            for (int i = 0; i < 8; ++i) {
                const bool free_ = !((msk >> i) & 1u);
                if (free_ && lv[i] > best) { best = lv[i]; bi = 8 * tj + i; braw = rv[i]; }
            }
            #pragma unroll
            for (int off = 1; off <= 4; off <<= 1) { // butterfly over 8-lane group
                const float ov  = __shfl_xor(best, off);
                const int   oi  = __shfl_xor(bi,   off);
                const float orw = __shfl_xor(braw, off);
                if (ov > best || (ov == best && oi < bi)) { best = ov; bi = oi; braw = orw; }
            }
            if (kk > 0) gmin = fminf(gmin, prev - best);
            prev = best;
            if (kk < K_SEL) {
                if ((bi >> 3) == tj) msk |= 1u << (bi & 7);
                selidx[kk] = bi;
                selraw[kk] = braw;
            }
        }

        if (gmin < EPS_GAP) {
            if (tj == 0) {
                unsigned int pp = atomicAdd(nfix, 1u);
                list[pp] = (unsigned int)grow;
            }
        } else {
            float mx = -INFINITY;
            #pragma unroll
            for (int kk = 0; kk < K_SEL; ++kk) mx = fmaxf(mx, selraw[kk]);
            float e[K_SEL], ssum = 0.f;
            #pragma unroll
            for (int kk = 0; kk < K_SEL; ++kk) { e[kk] = expf(selraw[kk] - mx); ssum += e[kk]; }
            float myp = 0.f; int myi = 0;
            #pragma unroll
            for (int kk = 0; kk < K_SEL; ++kk)
                if (kk == tj) { myp = e[kk] / ssum; myi = selidx[kk]; }
            out_sel  [(size_t)grow * K_SEL + tj] = (float)myi;
            out_probs[(size_t)grow * K_SEL + tj] = myp;
            if (am[grow]) {
                atomicAdd(&cnt[myi], 1u);
                if (tj == 0) atomicAdd(&cnt[L], 1u);
            }
        }
    }
    __syncthreads();
    if (t < L + 1 && cnt[t]) atomicAdd(&g_counts[t], cnt[t]);
}

// ----------------------------------------------------- fixup + finalize ----
// wave-per-row exact fp64 recompute (proven), then the LAST block (done-
// counter + threadfence + atomic reads) computes the loss scalars.
__global__ __launch_bounds__(256)
void fixup_fin(const float* __restrict__ x, const float* __restrict__ Wt,
               const float* __restrict__ bias, const unsigned char* __restrict__ am,
               const unsigned int* __restrict__ nfix, const unsigned int* __restrict__ list,
               float* __restrict__ out_sel, float* __restrict__ out_probs,
               unsigned int* __restrict__ g_counts, unsigned int* __restrict__ done,
               float* __restrict__ out_scalars)
{
    const int lane = threadIdx.x & 63;
    const int wid  = (blockIdx.x << 2) | (threadIdx.x >> 6);
    const int nw   = gridDim.x << 2;
    const int n    = (int)*nfix;
    const double bl = (double)bias[lane];

    for (int i = wid; i < n; i += nw) {
        const int row = (int)list[i];
        const float* xr = x + (size_t)row * H;
        double a0 = 0.0, a1 = 0.0, a2 = 0.0, a3 = 0.0;
        #pragma unroll 2
        for (int k = 0; k < H; k += 16) {
            float4 x0 = *(const float4*)(xr + k);
            float4 x1 = *(const float4*)(xr + k + 4);
            float4 x2 = *(const float4*)(xr + k + 8);
            float4 x3 = *(const float4*)(xr + k + 12);
            a0 = fma((double)x0.x, (double)Wt[(k +  0) * L + lane], a0);
            a1 = fma((double)x0.y, (double)Wt[(k +  1) * L + lane], a1);
            a2 = fma((double)x0.z, (double)Wt[(k +  2) * L + lane], a2);
            a3 = fma((double)x0.w, (double)Wt[(k +  3) * L + lane], a3);
            a0 = fma((double)x1.x, (double)Wt[(k +  4) * L + lane], a0);
            a1 = fma((double)x1.y, (double)Wt[(k +  5) * L + lane], a1);
            a2 = fma((double)x1.z, (double)Wt[(k +  6) * L + lane], a2);
            a3 = fma((double)x1.w, (double)Wt[(k +  7) * L + lane], a3);
            a0 = fma((double)x2.x, (double)Wt[(k +  8) * L + lane], a0);
            a1 = fma((double)x2.y, (double)Wt[(k +  9) * L + lane], a1);
            a2 = fma((double)x2.z, (double)Wt[(k + 10) * L + lane], a2);
            a3 = fma((double)x2.w, (double)Wt[(k + 11) * L + lane], a3);
            a0 = fma((double)x3.x, (double)Wt[(k + 12) * L + lane], a0);
            a1 = fma((double)x3.y, (double)Wt[(k + 13) * L + lane], a1);
            a2 = fma((double)x3.z, (double)Wt[(k + 14) * L + lane], a2);
            a3 = fma((double)x3.w, (double)Wt[(k + 15) * L + lane], a3);
        }
        double acc = (a0 + a1) + (a2 + a3);

        double v = acc + bl;
        int    widx[K_SEL];
        double wlog[K_SEL];
        #pragma unroll
        for (int kk = 0; kk < K_SEL; ++kk) {
            double mv = v; int mi = lane;
            #pragma unroll
            for (int off = 32; off; off >>= 1) {
                double ov = __shfl_xor(mv, off);
                int    oi = __shfl_xor(mi, off);
                if (ov > mv || (ov == mv && oi < mi)) { mv = ov; mi = oi; }
            }
            widx[kk] = mi;
            wlog[kk] = __shfl(acc, mi);
            if (lane == mi) v = -INFINITY;
        }

        double mx = -INFINITY;
        #pragma unroll
        for (int kk = 0; kk < K_SEL; ++kk) mx = fmax(mx, wlog[kk]);
        float e[K_SEL], ssum = 0.f;
        #pragma unroll
        for (int kk = 0; kk < K_SEL; ++kk) { e[kk] = expf((float)(wlog[kk] - mx)); ssum += e[kk]; }

        if (lane < K_SEL) {
            out_sel[(size_t)row * K_SEL + lane]   = (float)widx[lane];
            out_probs[(size_t)row * K_SEL + lane] = e[lane] / ssum;
        }
        if (am[row]) {
            if (lane < K_SEL)  atomicAdd(&g_counts[widx[lane]], 1u);
            if (lane == K_SEL) atomicAdd(&g_counts[L], 1u);
        }
    }

    // ---- finalize handoff: last block to finish computes the scalars
    __shared__ bool last;
    __syncthreads();
    if (threadIdx.x == 0) {
        __threadfence();                       // publish this block's atomics
        last = (atomicAdd(done, 1u) == (unsigned)gridDim.x - 1u);
    }
    __syncthreads();
    if (!last) return;

    const int l = threadIdx.x;
    if (l < L) {
        const unsigned cl = atomicAdd(&g_counts[l], 0u);   // coherent read
        const unsigned ct = atomicAdd(&g_counts[L], 0u);
        const float denom = (float)ct * (float)K_SEL;
        const float f = (float)cl / denom;
        float d  = f - 1.0f / (float)L;
        float sq = d * d;
        #pragma unroll
        for (int o = 32; o > 0; o >>= 1) {
            sq += __shfl_down(sq, o);
            d = fmaxf(d, __shfl_down(d, o));
        }
        if (l == 0) {
            out_scalars[0] = (float)L * sq;  // load_balance_loss
            out_scalars[1] = (float)L * d;   // max_vio
        }
    }
}

extern "C" void kernel_launch(void* const* d_in, const int* in_sizes, int n_in,
                              void* d_out, int out_size, void* d_ws, size_t ws_size,
                              hipStream_t stream)
{
    const float* x          = (const float*)d_in[0];
    const float* Wr         = (const float*)d_in[1];
    const float* bias       = (const float*)d_in[2];
    const unsigned char* am = (const unsigned char*)d_in[3];
    float* out = (float*)d_out;
    float* wsf = (float*)d_ws;
    unsigned int* wsu = (unsigned int*)d_ws;

    const int rows = in_sizes[3];  // B*N = 16384

    float* out_sel   = out;
    float* out_probs = out + (size_t)rows * K_SEL;
    float* out_scal  = out + (size_t)rows * K_SEL * 2;

    short* whc = (short*)(wsu + WS_WHC);
    short* wlc = (short*)(wsu + WS_WLC);

    hipLaunchKernelGGL(prep,        dim3(65),         dim3(256), 0, stream,
                       Wr, wsf + WS_WT, wsu, whc, wlc);
    hipLaunchKernelGGL(router_mfma, dim3(rows / RPB), dim3(256), 0, stream,
                       x, whc, wlc, bias, am, out_sel, out_probs,
                       wsu + WS_COUNTS, wsu + WS_NFIX, wsu + WS_LIST);
    hipLaunchKernelGGL(fixup_fin,   dim3(256),        dim3(256), 0, stream,
                       x, wsf + WS_WT, bias, am, wsu + WS_NFIX, wsu + WS_LIST,
                       out_sel, out_probs, wsu + WS_COUNTS, wsu + WS_DONE,
                       out_scal);
}

// Round 9
// 276.498 us; speedup vs baseline: 1.0397x; 1.0397x over previous
//
#include <hip/hip_runtime.h>
#include <stdint.h>
#include <math.h>

// Problem constants (fixed by setup_inputs: B=4, N=4096, H=2048, L=64, K=8)
constexpr int H     = 2048;
constexpr int L     = 64;
constexpr int K_SEL = 8;

// Direct-to-register MFMA geometry (r9): block = 256 thr (4 waves), 32 rows x
// 64 experts, grid 512 = 2 blocks/CU, launch_bounds(256,2) -> 256-VGPR budget.
// r8 lesson: (256,4)'s 128-VGPR cap made the compiler DROP the prefetch
// (VGPR=44, serial load->use, 87us). r9: burst-load x 4 chunks ahead into a
// fully-unrolled register file (16 loads = 32KB in flight/wave), pinned with
// sched_barrier(0); W loads direct per chunk (L2-resident, in-order vmcnt
// means the x burst completes before any same-quarter W wait).
constexpr int RPB   = 32;        // rows per block
constexpr int NCH   = 16;        // k-chunks per wave (64 total / 4 waves)

// EPS: bf16 hi/lo split noise sigma ~3e-6; 1e-4 = >30 sigma. Flagged rows
// (~200) get exact fp64 recompute.
constexpr float EPS_GAP = 1e-4f;

// ws layout (4-byte units)
constexpr int WS_COUNTS = 0;         // uint[65]: per-expert counts + [64]=active rows
constexpr int WS_NFIX   = 128;       // uint: fixup-row count
constexpr int WS_DONE   = 192;       // uint: fixup block done-counter (fused finalize)
constexpr int WS_LIST   = 256;       // uint[16384]: fixup row indices
constexpr int WS_WT     = 16640;     // float[2048*64]: W^T for coalesced fp64 fixup
constexpr int WS_WHC    = 147712;    // short[64*2048]: W hi bf16, chunked [c][e][32]
constexpr int WS_WLC    = 213248;    // short[64*2048]: W lo bf16, same layout

typedef __attribute__((ext_vector_type(8))) short bf16x8;
typedef __attribute__((ext_vector_type(4))) float f32x4;

// hi = RNE-bf16(x); lo = bf16(x - hi) (truncated; residual <= 2^-17|x|)
__device__ __forceinline__ void cvt_hi_lo(float c, short& h, short& l)
{
    unsigned u  = __float_as_uint(c);
    unsigned hb = (u + 0x7fffu + ((u >> 16) & 1u)) >> 16;
    float hf    = __uint_as_float(hb << 16);
    float lof   = c - hf;                      // exact in fp32
    h = (short)hb;
    l = (short)(__float_as_uint(lof) >> 16);
}

__device__ __forceinline__ void cvt8(const float4& u0, const float4& u1,
                                     bf16x8& h, bf16x8& l)
{
    short hh, ll;
    cvt_hi_lo(u0.x, hh, ll); h[0] = hh; l[0] = ll;
    cvt_hi_lo(u0.y, hh, ll); h[1] = hh; l[1] = ll;
    cvt_hi_lo(u0.z, hh, ll); h[2] = hh; l[2] = ll;
    cvt_hi_lo(u0.w, hh, ll); h[3] = hh; l[3] = ll;
    cvt_hi_lo(u1.x, hh, ll); h[4] = hh; l[4] = ll;
    cvt_hi_lo(u1.y, hh, ll); h[5] = hh; l[5] = ll;
    cvt_hi_lo(u1.z, hh, ll); h[6] = hh; l[6] = ll;
    cvt_hi_lo(u1.w, hh, ll); h[7] = hh; l[7] = ll;
}

// 3-product hi/lo MFMA: c += ah*bh + ah*bl + al*bh
__device__ __forceinline__ f32x4 mm3(const bf16x8& ah, const bf16x8& al,
                                     const bf16x8& bh, const bf16x8& bl, f32x4 c)
{
    c = __builtin_amdgcn_mfma_f32_16x16x32_bf16(ah, bh, c, 0, 0, 0);
    c = __builtin_amdgcn_mfma_f32_16x16x32_bf16(ah, bl, c, 0, 0, 0);
    c = __builtin_amdgcn_mfma_f32_16x16x32_bf16(al, bh, c, 0, 0, 0);
    return c;
}

// ---------------------------------------------------------------- prep ----
// blocks [0,32): transpose W -> Wt (fp64 fixup path); block 32: zero counters;
// blocks [33,65): convert W -> chunked bf16 hi/lo [kchunk][expert][32].
__global__ __launch_bounds__(256)
void prep(const float* __restrict__ Wr, float* __restrict__ Wt,
          unsigned int* __restrict__ wsu, short* __restrict__ whc,
          short* __restrict__ wlc)
{
    const int t = threadIdx.x, b = blockIdx.x;
    if (b == 32) {
        if (t < L + 1) wsu[WS_COUNTS + t] = 0u;
        if (t == 0)    wsu[WS_NFIX] = 0u;
        if (t == 1)    wsu[WS_DONE] = 0u;
        return;
    }
    if (b >= 33) {   // 32 blocks x 2 experts each; 512 float4 per expert
        const int z = b - 33;
        const int e = 2 * z + (t >> 7);
        const int idx = t & 127;
        #pragma unroll
        for (int u = 0; u < 4; ++u) {
            const int f4i = idx + 128 * u;         // 0..511
            const int k   = 4 * f4i;
            const float4 v = ((const float4*)(Wr + (size_t)e * H))[f4i];
            short4 hh, ll;
            cvt_hi_lo(v.x, hh.x, ll.x);
            cvt_hi_lo(v.y, hh.y, ll.y);
            cvt_hi_lo(v.z, hh.z, ll.z);
            cvt_hi_lo(v.w, hh.w, ll.w);
            const int c  = k >> 5, kk = k & 31;
            const int di = (c * 64 + e) * 32 + kk;
            *(short4*)(whc + di) = hh;
            *(short4*)(wlc + di) = ll;
        }
        return;
    }
    __shared__ float tile[64 * 65];
    const int k0 = b * 64;
    {
        const int l = t >> 2, kq = (t & 3) * 16;
        #pragma unroll
        for (int j = 0; j < 4; ++j) {
            float4 v = *(const float4*)(Wr + (size_t)l * H + k0 + kq + 4 * j);
            int k = kq + 4 * j;
            tile[(k + 0) * 65 + l] = v.x;
            tile[(k + 1) * 65 + l] = v.y;
            tile[(k + 2) * 65 + l] = v.z;
            tile[(k + 3) * 65 + l] = v.w;
        }
    }
    __syncthreads();
    {
        const int k = t >> 2, lq = (t & 3) * 16;
        #pragma unroll
        for (int j = 0; j < 4; ++j) {
            int l2 = lq + 4 * j;
            float4 o = make_float4(tile[k * 65 + l2], tile[k * 65 + l2 + 1],
                                   tile[k * 65 + l2 + 2], tile[k * 65 + l2 + 3]);
            *(float4*)(Wt + (size_t)(k0 + k) * L + l2) = o;
        }
    }
}

// ---------------------------------------------------------------- main ----
__global__ __launch_bounds__(256, 2)
void router_mfma(const float* __restrict__ x, const short* __restrict__ whc,
                 const short* __restrict__ wlc, const float* __restrict__ bias,
                 const unsigned char* __restrict__ am,
                 float* __restrict__ out_sel, float* __restrict__ out_probs,
                 unsigned int* __restrict__ g_counts, unsigned int* __restrict__ nfix,
                 unsigned int* __restrict__ list)
{
    __shared__ __align__(16) float lg[4 * RPB * 68];   // 34,816 B: 4 wave-partials
    __shared__ float bs[L];
    __shared__ unsigned int cnt[L + 1];

    const int t  = threadIdx.x;
    const int R0 = blockIdx.x * RPB;
    const int w  = t >> 6, l = t & 63;
    const int fr = l & 15;            // fragment row/col index
    const int kg = l >> 4;            // k-group 0..3
    const int kb = 8 * kg;            // k-base within a 32-k chunk

    if (t < L)     bs[t]  = bias[t];
    if (t < L + 1) cnt[t] = 0;

    // 8 named accumulators: acc_<rg><cg>, rg in {0,1} (rows), cg in {0..3} (cols)
    f32x4 acc_00 = {}, acc_01 = {}, acc_02 = {}, acc_03 = {};
    f32x4 acc_10 = {}, acc_11 = {}, acc_12 = {}, acc_13 = {};

    const float* xp0 = x + (size_t)(R0 + fr) * H + kb;        // rg0 row
    const float* xp1 = xp0 + (size_t)16 * H;                  // rg1 row
    const short* whp = whc + fr * 32 + kb;
    const short* wlp = wlc + fr * 32 + kb;

    // wave w covers chunks [16w, 16w+16) in 4 quarters. Per quarter: burst-
    // issue ALL 16 x-loads (32KB in flight), sched_barrier pins the order,
    // then consume 4 chunks (W loads direct; in-order vmcnt => x landed).
    {
        const int c0 = NCH * w;
        #pragma unroll
        for (int q = 0; q < 4; ++q) {
            float4 xa[4][4];
            #pragma unroll
            for (int ci = 0; ci < 4; ++ci) {
                const int xo = 32 * (c0 + 4 * q + ci);
                xa[ci][0] = *(const float4*)(xp0 + xo);
                xa[ci][1] = *(const float4*)(xp0 + xo + 4);
                xa[ci][2] = *(const float4*)(xp1 + xo);
                xa[ci][3] = *(const float4*)(xp1 + xo + 4);
            }
            __builtin_amdgcn_sched_barrier(0);   // all 16 loads issue first
            #pragma unroll
            for (int ci = 0; ci < 4; ++ci) {
                const int wo = 2048 * (c0 + 4 * q + ci);
                const bf16x8 bh0 = *(const bf16x8*)(whp + wo);
                const bf16x8 bh1 = *(const bf16x8*)(whp + wo + 512);
                const bf16x8 bh2 = *(const bf16x8*)(whp + wo + 1024);
                const bf16x8 bh3 = *(const bf16x8*)(whp + wo + 1536);
                const bf16x8 bl0 = *(const bf16x8*)(wlp + wo);
                const bf16x8 bl1 = *(const bf16x8*)(wlp + wo + 512);
                const bf16x8 bl2 = *(const bf16x8*)(wlp + wo + 1024);
                const bf16x8 bl3 = *(const bf16x8*)(wlp + wo + 1536);

                bf16x8 ah0, al0, ah1, al1;
                cvt8(xa[ci][0], xa[ci][1], ah0, al0);
                cvt8(xa[ci][2], xa[ci][3], ah1, al1);

                acc_00 = mm3(ah0, al0, bh0, bl0, acc_00);
                acc_01 = mm3(ah0, al0, bh1, bl1, acc_01);
                acc_02 = mm3(ah0, al0, bh2, bl2, acc_02);
                acc_03 = mm3(ah0, al0, bh3, bl3, acc_03);
                acc_10 = mm3(ah1, al1, bh0, bl0, acc_10);
                acc_11 = mm3(ah1, al1, bh1, bl1, acc_11);
                acc_12 = mm3(ah1, al1, bh2, bl2, acc_12);
                acc_13 = mm3(ah1, al1, bh3, bl3, acc_13);
            }
        }
    }

    // park partials: D layout col=lane&15, row=4*(lane>>4)+reg [m89-verified]
    {
        float* lgw = lg + w * (RPB * 68);
        const int rb = 4 * kg;
        #pragma unroll
        for (int r = 0; r < 4; ++r) {
            lgw[(rb + r)      * 68 + fr     ] = acc_00[r];
            lgw[(rb + r)      * 68 + fr + 16] = acc_01[r];
            lgw[(rb + r)      * 68 + fr + 32] = acc_02[r];
            lgw[(rb + r)      * 68 + fr + 48] = acc_03[r];
            lgw[(rb + r + 16) * 68 + fr     ] = acc_10[r];
            lgw[(rb + r + 16) * 68 + fr + 16] = acc_11[r];
            lgw[(rb + r + 16) * 68 + fr + 32] = acc_12[r];
            lgw[(rb + r + 16) * 68 + fr + 48] = acc_13[r];
        }
    }
    __syncthreads();

    // 4-way merge into lg[0] (2176 floats = 8.5 * 256)
    #pragma unroll
    for (int q = 0; q < 9; ++q) {
        const int p = t + 256 * q;
        if (p < RPB * 68)
            lg[p] = (lg[p] + lg[RPB * 68 + p]) + (lg[2 * RPB * 68 + p] + lg[3 * RPB * 68 + p]);
    }
    __syncthreads();

    // ---- top-9 epilogue: 8 lanes per row (proven r4/r6/r7 structure)
    {
        const int tj   = t & 7;
        const int lrow = t >> 3;             // 0..31
        const int grow = R0 + lrow;

        float rv[8], lv[8];
        {
            const float* lp = &lg[lrow * 68 + 8 * tj];
            const float4 v0 = *(const float4*)(lp);
            const float4 v1 = *(const float4*)(lp + 4);
            rv[0] = v0.x; rv[1] = v0.y; rv[2] = v0.z; rv[3] = v0.w;
            rv[4] = v1.x; rv[5] = v1.y; rv[6] = v1.z; rv[7] = v1.w;
            #pragma unroll
            for (int i = 0; i < 8; ++i) lv[i] = rv[i] + bs[8 * tj + i];
        }

        unsigned msk = 0;
        int   selidx[K_SEL];
        float selraw[K_SEL];
        float prev = 0.f, gmin = INFINITY;

        #pragma unroll
        for (int kk = 0; kk < K_SEL + 1; ++kk) {     // 9 rounds: gap rank8->rank9
            float best = -INFINITY; int bi = 1 << 30; float braw = 0.f;
            #pragma unroll
            for (int i = 0; i < 8; ++i) {
                const bool free_ = !((msk >> i) & 1u);
                if (free_ && lv[i] > best) { best = lv[i]; bi = 8 * tj + i; braw = rv[i]; }
            }
            #pragma unroll
            for (int off = 1; off <= 4; off <<= 1) { // butterfly over 8-lane group
                const float ov  = __shfl_xor(best, off);
                const int   oi  = __shfl_xor(bi,   off);
                const float orw = __shfl_xor(braw, off);
                if (ov > best || (ov == best && oi < bi)) { best = ov; bi = oi; braw = orw; }
            }
            if (kk > 0) gmin = fminf(gmin, prev - best);
            prev = best;
            if (kk < K_SEL) {
                if ((bi >> 3) == tj) msk |= 1u << (bi & 7);
                selidx[kk] = bi;
                selraw[kk] = braw;
            }
        }

        if (gmin < EPS_GAP) {
            if (tj == 0) {
                unsigned int pp = atomicAdd(nfix, 1u);
                list[pp] = (unsigned int)grow;
            }
        } else {
            float mx = -INFINITY;
            #pragma unroll
            for (int kk = 0; kk < K_SEL; ++kk) mx = fmaxf(mx, selraw[kk]);
            float e[K_SEL], ssum = 0.f;
            #pragma unroll
            for (int kk = 0; kk < K_SEL; ++kk) { e[kk] = expf(selraw[kk] - mx); ssum += e[kk]; }
            float myp = 0.f; int myi = 0;
            #pragma unroll
            for (int kk = 0; kk < K_SEL; ++kk)
                if (kk == tj) { myp = e[kk] / ssum; myi = selidx[kk]; }
            out_sel  [(size_t)grow * K_SEL + tj] = (float)myi;
            out_probs[(size_t)grow * K_SEL + tj] = myp;
            if (am[grow]) {
                atomicAdd(&cnt[myi], 1u);
                if (tj == 0) atomicAdd(&cnt[L], 1u);
            }
        }
    }
    __syncthreads();
    if (t < L + 1 && cnt[t]) atomicAdd(&g_counts[t], cnt[t]);
}

// ----------------------------------------------------- fixup + finalize ----
// wave-per-row exact fp64 recompute (proven), then the LAST block (done-
// counter + threadfence + atomic reads) computes the loss scalars.
__global__ __launch_bounds__(256)
void fixup_fin(const float* __restrict__ x, const float* __restrict__ Wt,
               const float* __restrict__ bias, const unsigned char* __restrict__ am,
               const unsigned int* __restrict__ nfix, const unsigned int* __restrict__ list,
               float* __restrict__ out_sel, float* __restrict__ out_probs,
               unsigned int* __restrict__ g_counts, unsigned int* __restrict__ done,
               float* __restrict__ out_scalars)
{
    const int lane = threadIdx.x & 63;
    const int wid  = (blockIdx.x << 2) | (threadIdx.x >> 6);
    const int nw   = gridDim.x << 2;
    const int n    = (int)*nfix;
    const double bl = (double)bias[lane];

    for (int i = wid; i < n; i += nw) {
        const int row = (int)list[i];
        const float* xr = x + (size_t)row * H;
        double a0 = 0.0, a1 = 0.0, a2 = 0.0, a3 = 0.0;
        #pragma unroll 2
        for (int k = 0; k < H; k += 16) {
            float4 x0 = *(const float4*)(xr + k);
            float4 x1 = *(const float4*)(xr + k + 4);
            float4 x2 = *(const float4*)(xr + k + 8);
            float4 x3 = *(const float4*)(xr + k + 12);
            a0 = fma((double)x0.x, (double)Wt[(k +  0) * L + lane], a0);
            a1 = fma((double)x0.y, (double)Wt[(k +  1) * L + lane], a1);
            a2 = fma((double)x0.z, (double)Wt[(k +  2) * L + lane], a2);
            a3 = fma((double)x0.w, (double)Wt[(k +  3) * L + lane], a3);
            a0 = fma((double)x1.x, (double)Wt[(k +  4) * L + lane], a0);
            a1 = fma((double)x1.y, (double)Wt[(k +  5) * L + lane], a1);
            a2 = fma((double)x1.z, (double)Wt[(k +  6) * L + lane], a2);
            a3 = fma((double)x1.w, (double)Wt[(k +  7) * L + lane], a3);
            a0 = fma((double)x2.x, (double)Wt[(k +  8) * L + lane], a0);
            a1 = fma((double)x2.y, (double)Wt[(k +  9) * L + lane], a1);
            a2 = fma((double)x2.z, (double)Wt[(k + 10) * L + lane], a2);
            a3 = fma((double)x2.w, (double)Wt[(k + 11) * L + lane], a3);
            a0 = fma((double)x3.x, (double)Wt[(k + 12) * L + lane], a0);
            a1 = fma((double)x3.y, (double)Wt[(k + 13) * L + lane], a1);
            a2 = fma((double)x3.z, (double)Wt[(k + 14) * L + lane], a2);
            a3 = fma((double)x3.w, (double)Wt[(k + 15) * L + lane], a3);
        }
        double acc = (a0 + a1) + (a2 + a3);

        double v = acc + bl;
        int    widx[K_SEL];
        double wlog[K_SEL];
        #pragma unroll
        for (int kk = 0; kk < K_SEL; ++kk) {
            double mv = v; int mi = lane;
            #pragma unroll
            for (int off = 32; off; off >>= 1) {
                double ov = __shfl_xor(mv, off);
                int    oi = __shfl_xor(mi, off);
                if (ov > mv || (ov == mv && oi < mi)) { mv = ov; mi = oi; }
            }
            widx[kk] = mi;
            wlog[kk] = __shfl(acc, mi);
            if (lane == mi) v = -INFINITY;
        }

        double mx = -INFINITY;
        #pragma unroll
        for (int kk = 0; kk < K_SEL; ++kk) mx = fmax(mx, wlog[kk]);
        float e[K_SEL], ssum = 0.f;
        #pragma unroll
        for (int kk = 0; kk < K_SEL; ++kk) { e[kk] = expf((float)(wlog[kk] - mx)); ssum += e[kk]; }

        if (lane < K_SEL) {
            out_sel[(size_t)row * K_SEL + lane]   = (float)widx[lane];
            out_probs[(size_t)row * K_SEL + lane] = e[lane] / ssum;
        }
        if (am[row]) {
            if (lane < K_SEL)  atomicAdd(&g_counts[widx[lane]], 1u);
            if (lane == K_SEL) atomicAdd(&g_counts[L], 1u);
        }
    }

    // ---- finalize handoff: last block to finish computes the scalars
    __shared__ bool last;
    __syncthreads();
    if (threadIdx.x == 0) {
        __threadfence();                       // publish this block's atomics
        last = (atomicAdd(done, 1u) == (unsigned)gridDim.x - 1u);
    }
    __syncthreads();
    if (!last) return;

    const int l = threadIdx.x;
    if (l < L) {
        const unsigned cl = atomicAdd(&g_counts[l], 0u);   // coherent read
        const unsigned ct = atomicAdd(&g_counts[L], 0u);
        const float denom = (float)ct * (float)K_SEL;
        const float f = (float)cl / denom;
        float d  = f - 1.0f / (float)L;
        float sq = d * d;
        #pragma unroll
        for (int o = 32; o > 0; o >>= 1) {
            sq += __shfl_down(sq, o);
            d = fmaxf(d, __shfl_down(d, o));
        }
        if (l == 0) {
            out_scalars[0] = (float)L * sq;  // load_balance_loss
            out_scalars[1] = (float)L * d;   // max_vio
        }
    }
}

extern "C" void kernel_launch(void* const* d_in, const int* in_sizes, int n_in,
                              void* d_out, int out_size, void* d_ws, size_t ws_size,
                              hipStream_t stream)
{
    const float* x          = (const float*)d_in[0];
    const float* Wr         = (const float*)d_in[1];
    const float* bias       = (const float*)d_in[2];
    const unsigned char* am = (const unsigned char*)d_in[3];
    float* out = (float*)d_out;
    float* wsf = (float*)d_ws;
    unsigned int* wsu = (unsigned int*)d_ws;

    const int rows = in_sizes[3];  // B*N = 16384

    float* out_sel   = out;
    float* out_probs = out + (size_t)rows * K_SEL;
    float* out_scal  = out + (size_t)rows * K_SEL * 2;

    short* whc = (short*)(wsu + WS_WHC);
    short* wlc = (short*)(wsu + WS_WLC);

    hipLaunchKernelGGL(prep,        dim3(65),         dim3(256), 0, stream,
                       Wr, wsf + WS_WT, wsu, whc, wlc);
    hipLaunchKernelGGL(router_mfma, dim3(rows / RPB), dim3(256), 0, stream,
                       x, whc, wlc, bias, am, out_sel, out_probs,
                       wsu + WS_COUNTS, wsu + WS_NFIX, wsu + WS_LIST);
    hipLaunchKernelGGL(fixup_fin,   dim3(256),        dim3(256), 0, stream,
                       x, wsf + WS_WT, bias, am, wsu + WS_NFIX, wsu + WS_LIST,
                       out_sel, out_probs, wsu + WS_COUNTS, wsu + WS_DONE,
                       out_scal);
}

// Round 10
// 273.703 us; speedup vs baseline: 1.0503x; 1.0102x over previous
//
#include <hip/hip_runtime.h>
#include <stdint.h>
#include <math.h>

// Problem constants (fixed by setup_inputs: B=4, N=4096, H=2048, L=64, K=8)
constexpr int H     = 2048;
constexpr int L     = 64;
constexpr int K_SEL = 8;

// r10 geometry: block = 256 thr (4 waves), 32 rows x 64 experts, grid 512 =
// 2 blocks/CU. Wave w owns expert-cols [16w,16w+16) for ALL rows (no K-split,
// no merge). x staged fp32 -> LDS in 8 stages of BK=256 via global_load_lds
// (bulk DMA, MLP=8/wave, ONE vmcnt drain per stage -- r7/r8/r9 lesson: the
// register path serializes loads at MLP~1, 90% stall). W read from L2 per
// chunk (2x16B) with 1-chunk register prefetch.
constexpr int RPB   = 32;        // rows per block
constexpr int BK    = 256;       // k per stage
constexpr int NSTG  = H / BK;    // 8 stages
constexpr int XROW  = 260;       // padded row stride (floats): b128 reads bank-uniform

// EPS: bf16 hi/lo split noise sigma ~3e-6; 1e-4 = >30 sigma. Flagged rows
// (~200) get exact fp64 recompute.
constexpr float EPS_GAP = 1e-4f;

// ws layout (4-byte units)
constexpr int WS_COUNTS = 0;         // uint[65]: per-expert counts + [64]=active rows
constexpr int WS_NFIX   = 128;       // uint: fixup-row count
constexpr int WS_DONE   = 192;       // uint: fixup block done-counter (fused finalize)
constexpr int WS_LIST   = 256;       // uint[16384]: fixup row indices
constexpr int WS_WT     = 16640;     // float[2048*64]: W^T for coalesced fp64 fixup
constexpr int WS_WHC    = 147712;    // short[64*2048]: W hi bf16, chunked [c][e][32]
constexpr int WS_WLC    = 213248;    // short[64*2048]: W lo bf16, same layout

typedef __attribute__((ext_vector_type(8))) short bf16x8;
typedef __attribute__((ext_vector_type(4))) float f32x4;

// async global->LDS, 16B per lane; LDS dest = wave-uniform base + lane*16
__device__ __forceinline__ void gld16(const float* g, float* l)
{
    __builtin_amdgcn_global_load_lds(
        (const __attribute__((address_space(1))) unsigned int*)g,
        (__attribute__((address_space(3))) unsigned int*)l, 16, 0, 0);
}

// hi = RNE-bf16(x); lo = bf16(x - hi) (truncated; residual <= 2^-17|x|)
__device__ __forceinline__ void cvt_hi_lo(float c, short& h, short& l)
{
    unsigned u  = __float_as_uint(c);
    unsigned hb = (u + 0x7fffu + ((u >> 16) & 1u)) >> 16;
    float hf    = __uint_as_float(hb << 16);
    float lof   = c - hf;                      // exact in fp32
    h = (short)hb;
    l = (short)(__float_as_uint(lof) >> 16);
}

__device__ __forceinline__ void cvt8(const float4& u0, const float4& u1,
                                     bf16x8& h, bf16x8& l)
{
    short hh, ll;
    cvt_hi_lo(u0.x, hh, ll); h[0] = hh; l[0] = ll;
    cvt_hi_lo(u0.y, hh, ll); h[1] = hh; l[1] = ll;
    cvt_hi_lo(u0.z, hh, ll); h[2] = hh; l[2] = ll;
    cvt_hi_lo(u0.w, hh, ll); h[3] = hh; l[3] = ll;
    cvt_hi_lo(u1.x, hh, ll); h[4] = hh; l[4] = ll;
    cvt_hi_lo(u1.y, hh, ll); h[5] = hh; l[5] = ll;
    cvt_hi_lo(u1.z, hh, ll); h[6] = hh; l[6] = ll;
    cvt_hi_lo(u1.w, hh, ll); h[7] = hh; l[7] = ll;
}

// 3-product hi/lo MFMA: c += ah*bh + ah*bl + al*bh
__device__ __forceinline__ f32x4 mm3(const bf16x8& ah, const bf16x8& al,
                                     const bf16x8& bh, const bf16x8& bl, f32x4 c)
{
    c = __builtin_amdgcn_mfma_f32_16x16x32_bf16(ah, bh, c, 0, 0, 0);
    c = __builtin_amdgcn_mfma_f32_16x16x32_bf16(ah, bl, c, 0, 0, 0);
    c = __builtin_amdgcn_mfma_f32_16x16x32_bf16(al, bh, c, 0, 0, 0);
    return c;
}

// ---------------------------------------------------------------- prep ----
// blocks [0,32): transpose W -> Wt (fp64 fixup path); block 32: zero counters;
// blocks [33,65): convert W -> chunked bf16 hi/lo [kchunk][expert][32].
__global__ __launch_bounds__(256)
void prep(const float* __restrict__ Wr, float* __restrict__ Wt,
          unsigned int* __restrict__ wsu, short* __restrict__ whc,
          short* __restrict__ wlc)
{
    const int t = threadIdx.x, b = blockIdx.x;
    if (b == 32) {
        if (t < L + 1) wsu[WS_COUNTS + t] = 0u;
        if (t == 0)    wsu[WS_NFIX] = 0u;
        if (t == 1)    wsu[WS_DONE] = 0u;
        return;
    }
    if (b >= 33) {   // 32 blocks x 2 experts each; 512 float4 per expert
        const int z = b - 33;
        const int e = 2 * z + (t >> 7);
        const int idx = t & 127;
        #pragma unroll
        for (int u = 0; u < 4; ++u) {
            const int f4i = idx + 128 * u;         // 0..511
            const int k   = 4 * f4i;
            const float4 v = ((const float4*)(Wr + (size_t)e * H))[f4i];
            short4 hh, ll;
            cvt_hi_lo(v.x, hh.x, ll.x);
            cvt_hi_lo(v.y, hh.y, ll.y);
            cvt_hi_lo(v.z, hh.z, ll.z);
            cvt_hi_lo(v.w, hh.w, ll.w);
            const int c  = k >> 5, kk = k & 31;
            const int di = (c * 64 + e) * 32 + kk;
            *(short4*)(whc + di) = hh;
            *(short4*)(wlc + di) = ll;
        }
        return;
    }
    __shared__ float tile[64 * 65];
    const int k0 = b * 64;
    {
        const int l = t >> 2, kq = (t & 3) * 16;
        #pragma unroll
        for (int j = 0; j < 4; ++j) {
            float4 v = *(const float4*)(Wr + (size_t)l * H + k0 + kq + 4 * j);
            int k = kq + 4 * j;
            tile[(k + 0) * 65 + l] = v.x;
            tile[(k + 1) * 65 + l] = v.y;
            tile[(k + 2) * 65 + l] = v.z;
            tile[(k + 3) * 65 + l] = v.w;
        }
    }
    __syncthreads();
    {
        const int k = t >> 2, lq = (t & 3) * 16;
        #pragma unroll
        for (int j = 0; j < 4; ++j) {
            int l2 = lq + 4 * j;
            float4 o = make_float4(tile[k * 65 + l2], tile[k * 65 + l2 + 1],
                                   tile[k * 65 + l2 + 2], tile[k * 65 + l2 + 3]);
            *(float4*)(Wt + (size_t)(k0 + k) * L + l2) = o;
        }
    }
}

// ---------------------------------------------------------------- main ----
__global__ __launch_bounds__(256, 2)
void router_mfma(const float* __restrict__ x, const short* __restrict__ whc,
                 const short* __restrict__ wlc, const float* __restrict__ bias,
                 const unsigned char* __restrict__ am,
                 float* __restrict__ out_sel, float* __restrict__ out_probs,
                 unsigned int* __restrict__ g_counts, unsigned int* __restrict__ nfix,
                 unsigned int* __restrict__ list)
{
    __shared__ __align__(16) float xs[2][RPB * XROW];  // 2 x 33,280 B
    __shared__ __align__(16) float lg[RPB * 68];       // 8,704 B
    __shared__ float bs[L];
    __shared__ unsigned int cnt[L + 1];

    const int t    = threadIdx.x;
    const int R0   = blockIdx.x * RPB;
    const int w    = t >> 6;
    const int lane = t & 63;
    const int fr   = lane & 15;       // A: row idx   B: expert-within-group
    const int kg   = lane >> 4;       // k-group 0..3
    const int kb   = 8 * kg;          // k-base within a 32-k chunk

    if (t < L)     bs[t]  = bias[t];
    if (t < L + 1) cnt[t] = 0;

    f32x4 acc0 = {}, acc1 = {};       // rows 0-15 / 16-31, expert-group w

    // W fragment addressing: chunk c -> c*2048 + w*512 + fr*32 + kb
    const short* whp = whc + w * 512 + fr * 32 + kb;
    const short* wlp = wlc + w * 512 + fr * 32 + kb;

    // prologue: stage 0 (wave w stages rows 8w..8w+8) + first W fragment
    #pragma unroll
    for (int j = 0; j < 8; ++j) {
        const int r = 8 * w + j;
        gld16(x + (size_t)(R0 + r) * H + 4 * lane, &xs[0][r * XROW]);
    }
    bf16x8 wh_c = *(const bf16x8*)(whp);
    bf16x8 wl_c = *(const bf16x8*)(wlp);
    __syncthreads();                  // drains the stage-0 DMA

    for (int s = 0; s < NSTG; ++s) {
        const int p = s & 1;
        // issue next stage's DMA (in flight across this stage's compute)
        if (s + 1 < NSTG) {
            const int k0n = BK * (s + 1);
            #pragma unroll
            for (int j = 0; j < 8; ++j) {
                const int r = 8 * w + j;
                gld16(x + (size_t)(R0 + r) * H + k0n + 4 * lane,
                      &xs[p ^ 1][r * XROW]);
            }
        }
        // consume 8 chunks of the current stage
        #pragma unroll
        for (int kc = 0; kc < 8; ++kc) {
            const int c = 8 * s + kc;
            bf16x8 wh_n = wh_c, wl_n = wl_c;
            if (c + 1 < 64) {         // 1-chunk W prefetch
                wh_n = *(const bf16x8*)(whp + 2048 * (c + 1));
                wl_n = *(const bf16x8*)(wlp + 2048 * (c + 1));
            }
            const float* x0 = &xs[p][fr * XROW + 32 * kc + kb];
            const float* x1 = &xs[p][(fr + 16) * XROW + 32 * kc + kb];
            const float4 a00 = *(const float4*)(x0);
            const float4 a01 = *(const float4*)(x0 + 4);
            const float4 a10 = *(const float4*)(x1);
            const float4 a11 = *(const float4*)(x1 + 4);
            bf16x8 ah0, al0, ah1, al1;
            cvt8(a00, a01, ah0, al0);
            cvt8(a10, a11, ah1, al1);
            acc0 = mm3(ah0, al0, wh_c, wl_c, acc0);
            acc1 = mm3(ah1, al1, wh_c, wl_c, acc1);
            wh_c = wh_n; wl_c = wl_n;
        }
        __syncthreads();              // one vmcnt drain per stage (8 total)
    }

    // write logits: D layout col=lane&15, row=4*(lane>>4)+reg [m89-verified]
    #pragma unroll
    for (int r = 0; r < 4; ++r) {
        lg[(4 * kg + r)      * 68 + 16 * w + fr] = acc0[r];
        lg[(4 * kg + r + 16) * 68 + 16 * w + fr] = acc1[r];
    }
    __syncthreads();

    // ---- top-9 epilogue: 8 lanes per row (proven r4/r6/r7 structure)
    {
        const int tj   = t & 7;
        const int lrow = t >> 3;             // 0..31
        const int grow = R0 + lrow;

        float rv[8], lv[8];
        {
            const float* lp = &lg[lrow * 68 + 8 * tj];
            const float4 v0 = *(const float4*)(lp);
            const float4 v1 = *(const float4*)(lp + 4);
            rv[0] = v0.x; rv[1] = v0.y; rv[2] = v0.z; rv[3] = v0.w;
            rv[4] = v1.x; rv[5] = v1.y; rv[6] = v1.z; rv[7] = v1.w;
            #pragma unroll
            for (int i = 0; i < 8; ++i) lv[i] = rv[i] + bs[8 * tj + i];
        }

        unsigned msk = 0;
        int   selidx[K_SEL];
        float selraw[K_SEL];
        float prev = 0.f, gmin = INFINITY;

        #pragma unroll
        for (int kk = 0; kk < K_SEL + 1; ++kk) {     // 9 rounds: gap rank8->rank9
            float best = -INFINITY; int bi = 1 << 30; float braw = 0.f;
            #pragma unroll
            for (int i = 0; i < 8; ++i) {
                const bool free_ = !((msk >> i) & 1u);
                if (free_ && lv[i] > best) { best = lv[i]; bi = 8 * tj + i; braw = rv[i]; }
            }
            #pragma unroll
            for (int off = 1; off <= 4; off <<= 1) { // butterfly over 8-lane group
                const float ov  = __shfl_xor(best, off);
                const int   oi  = __shfl_xor(bi,   off);
                const float orw = __shfl_xor(braw, off);
                if (ov > best || (ov == best && oi < bi)) { best = ov; bi = oi; braw = orw; }
            }
            if (kk > 0) gmin = fminf(gmin, prev - best);
            prev = best;
            if (kk < K_SEL) {
                if ((bi >> 3) == tj) msk |= 1u << (bi & 7);
                selidx[kk] = bi;
                selraw[kk] = braw;
            }
        }

        if (gmin < EPS_GAP) {
            if (tj == 0) {
                unsigned int pp = atomicAdd(nfix, 1u);
                list[pp] = (unsigned int)grow;
            }
        } else {
            float mx = -INFINITY;
            #pragma unroll
            for (int kk = 0; kk < K_SEL; ++kk) mx = fmaxf(mx, selraw[kk]);
            float e[K_SEL], ssum = 0.f;
            #pragma unroll
            for (int kk = 0; kk < K_SEL; ++kk) { e[kk] = expf(selraw[kk] - mx); ssum += e[kk]; }
            float myp = 0.f; int myi = 0;
            #pragma unroll
            for (int kk = 0; kk < K_SEL; ++kk)
                if (kk == tj) { myp = e[kk] / ssum; myi = selidx[kk]; }
            out_sel  [(size_t)grow * K_SEL + tj] = (float)myi;
            out_probs[(size_t)grow * K_SEL + tj] = myp;
            if (am[grow]) {
                atomicAdd(&cnt[myi], 1u);
                if (tj == 0) atomicAdd(&cnt[L], 1u);
            }
        }
    }
    __syncthreads();
    if (t < L + 1 && cnt[t]) atomicAdd(&g_counts[t], cnt[t]);
}

// ----------------------------------------------------- fixup + finalize ----
// wave-per-row exact fp64 recompute (proven), then the LAST block (done-
// counter + threadfence + atomic reads) computes the loss scalars.
__global__ __launch_bounds__(256)
void fixup_fin(const float* __restrict__ x, const float* __restrict__ Wt,
               const float* __restrict__ bias, const unsigned char* __restrict__ am,
               const unsigned int* __restrict__ nfix, const unsigned int* __restrict__ list,
               float* __restrict__ out_sel, float* __restrict__ out_probs,
               unsigned int* __restrict__ g_counts, unsigned int* __restrict__ done,
               float* __restrict__ out_scalars)
{
    const int lane = threadIdx.x & 63;
    const int wid  = (blockIdx.x << 2) | (threadIdx.x >> 6);
    const int nw   = gridDim.x << 2;
    const int n    = (int)*nfix;
    const double bl = (double)bias[lane];

    for (int i = wid; i < n; i += nw) {
        const int row = (int)list[i];
        const float* xr = x + (size_t)row * H;
        double a0 = 0.0, a1 = 0.0, a2 = 0.0, a3 = 0.0;
        #pragma unroll 2
        for (int k = 0; k < H; k += 16) {
            float4 x0 = *(const float4*)(xr + k);
            float4 x1 = *(const float4*)(xr + k + 4);
            float4 x2 = *(const float4*)(xr + k + 8);
            float4 x3 = *(const float4*)(xr + k + 12);
            a0 = fma((double)x0.x, (double)Wt[(k +  0) * L + lane], a0);
            a1 = fma((double)x0.y, (double)Wt[(k +  1) * L + lane], a1);
            a2 = fma((double)x0.z, (double)Wt[(k +  2) * L + lane], a2);
            a3 = fma((double)x0.w, (double)Wt[(k +  3) * L + lane], a3);
            a0 = fma((double)x1.x, (double)Wt[(k +  4) * L + lane], a0);
            a1 = fma((double)x1.y, (double)Wt[(k +  5) * L + lane], a1);
            a2 = fma((double)x1.z, (double)Wt[(k +  6) * L + lane], a2);
            a3 = fma((double)x1.w, (double)Wt[(k +  7) * L + lane], a3);
            a0 = fma((double)x2.x, (double)Wt[(k +  8) * L + lane], a0);
            a1 = fma((double)x2.y, (double)Wt[(k +  9) * L + lane], a1);
            a2 = fma((double)x2.z, (double)Wt[(k + 10) * L + lane], a2);
            a3 = fma((double)x2.w, (double)Wt[(k + 11) * L + lane], a3);
            a0 = fma((double)x3.x, (double)Wt[(k + 12) * L + lane], a0);
            a1 = fma((double)x3.y, (double)Wt[(k + 13) * L + lane], a1);
            a2 = fma((double)x3.z, (double)Wt[(k + 14) * L + lane], a2);
            a3 = fma((double)x3.w, (double)Wt[(k + 15) * L + lane], a3);
        }
        double acc = (a0 + a1) + (a2 + a3);

        double v = acc + bl;
        int    widx[K_SEL];
        double wlog[K_SEL];
        #pragma unroll
        for (int kk = 0; kk < K_SEL; ++kk) {
            double mv = v; int mi = lane;
            #pragma unroll
            for (int off = 32; off; off >>= 1) {
                double ov = __shfl_xor(mv, off);
                int    oi = __shfl_xor(mi, off);
                if (ov > mv || (ov == mv && oi < mi)) { mv = ov; mi = oi; }
            }
            widx[kk] = mi;
            wlog[kk] = __shfl(acc, mi);
            if (lane == mi) v = -INFINITY;
        }

        double mx = -INFINITY;
        #pragma unroll
        for (int kk = 0; kk < K_SEL; ++kk) mx = fmax(mx, wlog[kk]);
        float e[K_SEL], ssum = 0.f;
        #pragma unroll
        for (int kk = 0; kk < K_SEL; ++kk) { e[kk] = expf((float)(wlog[kk] - mx)); ssum += e[kk]; }

        if (lane < K_SEL) {
            out_sel[(size_t)row * K_SEL + lane]   = (float)widx[lane];
            out_probs[(size_t)row * K_SEL + lane] = e[lane] / ssum;
        }
        if (am[row]) {
            if (lane < K_SEL)  atomicAdd(&g_counts[widx[lane]], 1u);
            if (lane == K_SEL) atomicAdd(&g_counts[L], 1u);
        }
    }

    // ---- finalize handoff: last block to finish computes the scalars
    __shared__ bool last;
    __syncthreads();
    if (threadIdx.x == 0) {
        __threadfence();                       // publish this block's atomics
        last = (atomicAdd(done, 1u) == (unsigned)gridDim.x - 1u);
    }
    __syncthreads();
    if (!last) return;

    const int l = threadIdx.x;
    if (l < L) {
        const unsigned cl = atomicAdd(&g_counts[l], 0u);   // coherent read
        const unsigned ct = atomicAdd(&g_counts[L], 0u);
        const float denom = (float)ct * (float)K_SEL;
        const float f = (float)cl / denom;
        float d  = f - 1.0f / (float)L;
        float sq = d * d;
        #pragma unroll
        for (int o = 32; o > 0; o >>= 1) {
            sq += __shfl_down(sq, o);
            d = fmaxf(d, __shfl_down(d, o));
        }
        if (l == 0) {
            out_scalars[0] = (float)L * sq;  // load_balance_loss
            out_scalars[1] = (float)L * d;   // max_vio
        }
    }
}

extern "C" void kernel_launch(void* const* d_in, const int* in_sizes, int n_in,
                              void* d_out, int out_size, void* d_ws, size_t ws_size,
                              hipStream_t stream)
{
    const float* x          = (const float*)d_in[0];
    const float* Wr         = (const float*)d_in[1];
    const float* bias       = (const float*)d_in[2];
    const unsigned char* am = (const unsigned char*)d_in[3];
    float* out = (float*)d_out;
    float* wsf = (float*)d_ws;
    unsigned int* wsu = (unsigned int*)d_ws;

    const int rows = in_sizes[3];  // B*N = 16384

    float* out_sel   = out;
    float* out_probs = out + (size_t)rows * K_SEL;
    float* out_scal  = out + (size_t)rows * K_SEL * 2;

    short* whc = (short*)(wsu + WS_WHC);
    short* wlc = (short*)(wsu + WS_WLC);

    hipLaunchKernelGGL(prep,        dim3(65),         dim3(256), 0, stream,
                       Wr, wsf + WS_WT, wsu, whc, wlc);
    hipLaunchKernelGGL(router_mfma, dim3(rows / RPB), dim3(256), 0, stream,
                       x, whc, wlc, bias, am, out_sel, out_probs,
                       wsu + WS_COUNTS, wsu + WS_NFIX, wsu + WS_LIST);
    hipLaunchKernelGGL(fixup_fin,   dim3(256),        dim3(256), 0, stream,
                       x, wsf + WS_WT, bias, am, wsu + WS_NFIX, wsu + WS_LIST,
                       out_sel, out_probs, wsu + WS_COUNTS, wsu + WS_DONE,
                       out_scal);
}